// Round 1
// baseline (231.350 us; speedup 1.0000x reference)
//
#include <hip/hip_runtime.h>
#include <hip/hip_bf16.h>

typedef __bf16 bf16_t;
typedef __bf16 bf16x4 __attribute__((ext_vector_type(4)));
typedef __bf16 bf16x8 __attribute__((ext_vector_type(8)));
typedef float  f32x4  __attribute__((ext_vector_type(4)));

// ---------------------------------------------------------------------------
// proj_gemm: P[M,256] = A[M,K] @ W[256,K]^T + bias
// BM=128, BN=64, BK=32; 256 threads (4 waves, 2x2 wave grid, 64x32 per wave)
// fp32 inputs converted to bf16 during LDS staging; fp32 accumulate via MFMA.
// ---------------------------------------------------------------------------
__global__ __launch_bounds__(256) void proj_gemm(
    const float* __restrict__ A,    // [M, K]
    const float* __restrict__ W,    // [256, K]
    const float* __restrict__ bias, // [256]
    float* __restrict__ P,          // [M, 256]
    int K)
{
    __shared__ bf16_t As[128][32];
    __shared__ bf16_t Bs[64][32];

    const int tid  = threadIdx.x;
    const int lane = tid & 63;
    const int wave = tid >> 6;
    const int quad = lane >> 4;   // 0..3
    const int c16  = lane & 15;   // 0..15
    const int wy   = wave >> 1;   // 0..1 (row)
    const int wx   = wave & 1;    // 0..1 (col)
    const int rowBase = blockIdx.x * 128;
    const int colBase = blockIdx.y * 64;

    f32x4 acc[4][2] = {};         // FM=4 (64 rows/wave), FN=2 (32 cols/wave)

    const int sr = tid >> 3;      // 0..31  (row within staging pass)
    const int sc = tid & 7;       // 0..7   (float4 chunk)

    for (int k0 = 0; k0 < K; k0 += 32) {
        // A tile: 128x32 fp32 -> bf16, 4 passes of 32 rows
        #pragma unroll
        for (int p = 0; p < 4; ++p) {
            int row = p * 32 + sr;
            f32x4 v = *reinterpret_cast<const f32x4*>(
                &A[(size_t)(rowBase + row) * K + k0 + sc * 4]);
            bf16x4 h = { (bf16_t)v.x, (bf16_t)v.y, (bf16_t)v.z, (bf16_t)v.w };
            *reinterpret_cast<bf16x4*>(&As[row][sc * 4]) = h;
        }
        // B tile: 64x32 fp32 -> bf16, 2 passes
        #pragma unroll
        for (int p = 0; p < 2; ++p) {
            int row = p * 32 + sr;
            f32x4 v = *reinterpret_cast<const f32x4*>(
                &W[(size_t)(colBase + row) * K + k0 + sc * 4]);
            bf16x4 h = { (bf16_t)v.x, (bf16_t)v.y, (bf16_t)v.z, (bf16_t)v.w };
            *reinterpret_cast<bf16x4*>(&Bs[row][sc * 4]) = h;
        }
        __syncthreads();

        bf16x8 aF[4], bF[2];
        #pragma unroll
        for (int mf = 0; mf < 4; ++mf)
            aF[mf] = *reinterpret_cast<const bf16x8*>(&As[wy * 64 + mf * 16 + c16][quad * 8]);
        #pragma unroll
        for (int nf = 0; nf < 2; ++nf)
            bF[nf] = *reinterpret_cast<const bf16x8*>(&Bs[wx * 32 + nf * 16 + c16][quad * 8]);
        #pragma unroll
        for (int mf = 0; mf < 4; ++mf)
            #pragma unroll
            for (int nf = 0; nf < 2; ++nf)
                acc[mf][nf] = __builtin_amdgcn_mfma_f32_16x16x32_bf16(
                    aF[mf], bF[nf], acc[mf][nf], 0, 0, 0);
        __syncthreads();
    }

    // Epilogue: += bias, store fp32. C/D layout: col=lane&15, row=quad*4+reg
    #pragma unroll
    for (int nf = 0; nf < 2; ++nf) {
        int gcol = colBase + wx * 32 + nf * 16 + c16;
        float b = bias[gcol];
        #pragma unroll
        for (int mf = 0; mf < 4; ++mf) {
            #pragma unroll
            for (int r = 0; r < 4; ++r) {
                int grow = rowBase + wy * 64 + mf * 16 + quad * 4 + r;
                P[(size_t)grow * 256 + gcol] = acc[mf][nf][r] + b;
            }
        }
    }
}

// ---------------------------------------------------------------------------
// rownorm: L2-normalize rows of Xp (rows 0..8191) and Yp (rows 8192..16383),
// write bf16. One 64-lane wave per 256-wide row (float4 per lane).
// ---------------------------------------------------------------------------
__global__ __launch_bounds__(256) void rownorm(
    const float* __restrict__ Xp, const float* __restrict__ Yp,
    bf16_t* __restrict__ Xn, bf16_t* __restrict__ Yn)
{
    const int wave = threadIdx.x >> 6;
    const int lane = threadIdx.x & 63;
    const int r = blockIdx.x * 4 + wave;   // 0..16383

    const float* src;
    bf16_t* dst;
    int row;
    if (r < 8192) { src = Xp; dst = Xn; row = r; }
    else          { src = Yp; dst = Yn; row = r - 8192; }

    f32x4 v = *reinterpret_cast<const f32x4*>(&src[(size_t)row * 256 + lane * 4]);
    float s = v.x * v.x + v.y * v.y + v.z * v.z + v.w * v.w;
    #pragma unroll
    for (int o = 32; o >= 1; o >>= 1) s += __shfl_xor(s, o, 64);
    float inv = 1.0f / fmaxf(sqrtf(s), 1e-8f);

    bf16x4 h = { (bf16_t)(v.x * inv), (bf16_t)(v.y * inv),
                 (bf16_t)(v.z * inv), (bf16_t)(v.w * inv) };
    *reinterpret_cast<bf16x4*>(&dst[(size_t)row * 256 + lane * 4]) = h;
}

// ---------------------------------------------------------------------------
// sim_gemm: e = exp(Xn @ Yn^T), accumulate rowsum (over cols) and colsum
// (over rows) of e, and capture diagonal pos[j] = e[j,j].
// BM=BN=128, BK=32, K=256; 256 threads, 2x2 wave grid, 64x64 per wave.
// ---------------------------------------------------------------------------
__global__ __launch_bounds__(256) void sim_gemm(
    const bf16_t* __restrict__ Xn, const bf16_t* __restrict__ Yn,
    float* __restrict__ rowsum, float* __restrict__ colsum,
    float* __restrict__ pos)
{
    __shared__ bf16_t As[128][32];
    __shared__ bf16_t Bs[128][32];
    __shared__ float  red[256];   // [0:128) row partials, [128:256) col partials

    const int tid  = threadIdx.x;
    const int lane = tid & 63;
    const int wave = tid >> 6;
    const int quad = lane >> 4;
    const int c16  = lane & 15;
    const int wy   = wave >> 1;
    const int wx   = wave & 1;
    const int rowBase = blockIdx.x * 128;
    const int colBase = blockIdx.y * 128;

    f32x4 acc[4][4] = {};

    const int sr = tid >> 2;   // 0..63
    const int sc = tid & 3;    // 16B chunk (8 bf16)

    for (int k0 = 0; k0 < 256; k0 += 32) {
        #pragma unroll
        for (int p = 0; p < 2; ++p) {
            int row = p * 64 + sr;
            *reinterpret_cast<bf16x8*>(&As[row][sc * 8]) =
                *reinterpret_cast<const bf16x8*>(&Xn[(size_t)(rowBase + row) * 256 + k0 + sc * 8]);
            *reinterpret_cast<bf16x8*>(&Bs[row][sc * 8]) =
                *reinterpret_cast<const bf16x8*>(&Yn[(size_t)(colBase + row) * 256 + k0 + sc * 8]);
        }
        __syncthreads();

        bf16x8 aF[4], bF[4];
        #pragma unroll
        for (int mf = 0; mf < 4; ++mf)
            aF[mf] = *reinterpret_cast<const bf16x8*>(&As[wy * 64 + mf * 16 + c16][quad * 8]);
        #pragma unroll
        for (int nf = 0; nf < 4; ++nf)
            bF[nf] = *reinterpret_cast<const bf16x8*>(&Bs[wx * 64 + nf * 16 + c16][quad * 8]);
        #pragma unroll
        for (int mf = 0; mf < 4; ++mf)
            #pragma unroll
            for (int nf = 0; nf < 4; ++nf)
                acc[mf][nf] = __builtin_amdgcn_mfma_f32_16x16x32_bf16(
                    aF[mf], bF[nf], acc[mf][nf], 0, 0, 0);
        __syncthreads();
    }

    // ---- epilogue: exp, diag capture, row/col reductions ----
    #pragma unroll
    for (int mf = 0; mf < 4; ++mf)
        #pragma unroll
        for (int nf = 0; nf < 4; ++nf)
            #pragma unroll
            for (int r = 0; r < 4; ++r)
                acc[mf][nf][r] = __expf(acc[mf][nf][r]);   // TAU = 1

    // diagonal: only blocks with rowBase == colBase contain e[j,j]
    if (rowBase == colBase) {
        #pragma unroll
        for (int mf = 0; mf < 4; ++mf)
            #pragma unroll
            for (int nf = 0; nf < 4; ++nf)
                #pragma unroll
                for (int r = 0; r < 4; ++r) {
                    int lrow = wy * 64 + mf * 16 + quad * 4 + r;
                    int lcol = wx * 64 + nf * 16 + c16;
                    if (lrow == lcol) pos[rowBase + lrow] = acc[mf][nf][r];
                }
    }

    // row sums: sum over nf in-register, then butterfly over the 16 lanes of
    // each quad-group (cols). Every lane ends with the group sum.
    float rs[4][4];
    #pragma unroll
    for (int mf = 0; mf < 4; ++mf)
        #pragma unroll
        for (int r = 0; r < 4; ++r) {
            float v = acc[mf][0][r] + acc[mf][1][r] + acc[mf][2][r] + acc[mf][3][r];
            v += __shfl_xor(v, 1, 64);
            v += __shfl_xor(v, 2, 64);
            v += __shfl_xor(v, 4, 64);
            v += __shfl_xor(v, 8, 64);
            rs[mf][r] = v;
        }

    // col sums: sum over mf,r in-register, then butterfly across quads.
    float cs[4];
    #pragma unroll
    for (int nf = 0; nf < 4; ++nf) {
        float v = 0.f;
        #pragma unroll
        for (int mf = 0; mf < 4; ++mf)
            #pragma unroll
            for (int r = 0; r < 4; ++r)
                v += acc[mf][nf][r];
        v += __shfl_xor(v, 16, 64);
        v += __shfl_xor(v, 32, 64);
        cs[nf] = v;
    }

    red[tid] = 0.f;
    __syncthreads();

    if (c16 == 0) {   // 4 lanes/wave (one per quad) write 16 row partials each
        #pragma unroll
        for (int mf = 0; mf < 4; ++mf)
            #pragma unroll
            for (int r = 0; r < 4; ++r)
                atomicAdd(&red[wy * 64 + mf * 16 + quad * 4 + r], rs[mf][r]);
    }
    if (quad == 0) {  // 16 lanes/wave write 4 col partials each
        #pragma unroll
        for (int nf = 0; nf < 4; ++nf)
            atomicAdd(&red[128 + wx * 64 + nf * 16 + c16], cs[nf]);
    }
    __syncthreads();

    if (tid < 128) atomicAdd(&rowsum[rowBase + tid], red[tid]);
    else           atomicAdd(&colsum[colBase + tid - 128], red[tid]);
}

// ---------------------------------------------------------------------------
// finalize: out[j] = log(colsum_j - pos_j) + log(rowsum_j - pos_j) - 2 log(pos_j)
// ---------------------------------------------------------------------------
__global__ __launch_bounds__(256) void finalize(
    const float* __restrict__ rowsum, const float* __restrict__ colsum,
    const float* __restrict__ pos, float* __restrict__ out)
{
    int i = blockIdx.x * 256 + threadIdx.x;
    float p = pos[i];
    out[i] = logf(colsum[i] - p) + logf(rowsum[i] - p) - 2.0f * logf(p);
}

// ---------------------------------------------------------------------------
extern "C" void kernel_launch(void* const* d_in, const int* in_sizes, int n_in,
                              void* d_out, int out_size, void* d_ws, size_t ws_size,
                              hipStream_t stream) {
    const float* X  = (const float*)d_in[0];
    const float* Y  = (const float*)d_in[1];
    const float* Wx = (const float*)d_in[2];
    const float* bx = (const float*)d_in[3];
    const float* Wy = (const float*)d_in[4];
    const float* by = (const float*)d_in[5];
    float* out = (float*)d_out;

    char* ws = (char*)d_ws;
    float*  Xp = (float*)(ws);                     // 8 MB: 8192x256 fp32
    float*  Yp = (float*)(ws + (8u  << 20));       // 8 MB
    bf16_t* Xn = (bf16_t*)(ws + (16u << 20));      // 4 MB: 8192x256 bf16
    bf16_t* Yn = (bf16_t*)(ws + (20u << 20));      // 4 MB
    float*  rowsum = (float*)(ws + (24u << 20));   // 32 KB
    float*  colsum = rowsum + 8192;                // 32 KB
    float*  pos    = colsum + 8192;                // 32 KB

    hipMemsetAsync(rowsum, 0, 2 * 8192 * sizeof(float), stream);

    proj_gemm<<<dim3(64, 4), 256, 0, stream>>>(X, Wx, bx, Xp, 1024);
    proj_gemm<<<dim3(64, 4), 256, 0, stream>>>(Y, Wy, by, Yp, 768);
    rownorm<<<4096, 256, 0, stream>>>(Xp, Yp, Xn, Yn);
    sim_gemm<<<dim3(64, 64), 256, 0, stream>>>(Xn, Yn, rowsum, colsum, pos);
    finalize<<<32, 256, 0, stream>>>(rowsum, colsum, pos, out);
}

// Round 2
// 203.596 us; speedup vs baseline: 1.1363x; 1.1363x over previous
//
#include <hip/hip_runtime.h>
#include <hip/hip_bf16.h>

typedef __bf16 bf16_t;
typedef __bf16 bf16x4 __attribute__((ext_vector_type(4)));
typedef __bf16 bf16x8 __attribute__((ext_vector_type(8)));
typedef float  f32x4  __attribute__((ext_vector_type(4)));

// 16B async global->LDS DMA. LDS dest is wave-uniform base + lane*16.
__device__ __forceinline__ void gl_lds16(const void* g, void* l) {
    __builtin_amdgcn_global_load_lds(
        (const __attribute__((address_space(1))) unsigned int*)g,
        (__attribute__((address_space(3))) unsigned int*)l, 16, 0, 0);
}

// ---------------------------------------------------------------------------
// proj_gemm (fused X and Y): P[M,256] = A[M,K] @ W[256,K]^T + bias
// blockIdx.x in [0,128): X rows (K=1024); [128,256): Y rows (K=768).
// BM=64, BN=64, BK=64; 256 threads, 2x2 waves, 32x32 per wave.
// Register-pipelined staging: global loads for k+1 issued during iter k.
// ---------------------------------------------------------------------------
__global__ __launch_bounds__(256) void proj_gemm(
    const float* __restrict__ X, const float* __restrict__ Y,
    const float* __restrict__ Wxp, const float* __restrict__ bxp,
    const float* __restrict__ Wyp, const float* __restrict__ byp,
    float* __restrict__ Xp, float* __restrict__ Yp)
{
    __shared__ bf16_t As[64][72];   // +8 pad: frag reads 2-way (free)
    __shared__ bf16_t Bs[64][72];

    const int tid  = threadIdx.x;
    const int lane = tid & 63;
    const int wave = tid >> 6;
    const int quad = lane >> 4;
    const int c16  = lane & 15;
    const int wy   = wave >> 1;
    const int wx   = wave & 1;

    const bool isY = blockIdx.x >= 128;
    const float* A    = isY ? Y   : X;
    const float* W    = isY ? Wyp : Wxp;
    const float* bias = isY ? byp : bxp;
    float* P          = isY ? Yp  : Xp;
    const int K     = isY ? 768 : 1024;
    const int kit   = K >> 6;             // 12 or 16
    const int rowBase = (blockIdx.x & 127) * 64;
    const int colBase = blockIdx.y * 64;

    const int lr = tid >> 2;              // 0..63 tile row
    const int lc = tid & 3;               // 0..3 col group (16 floats)

    f32x4 ra[4], rb[4];
    const float* pa = &A[(size_t)(rowBase + lr) * K + lc * 16];
    const float* pw = &W[(size_t)(colBase + lr) * K + lc * 16];

    #pragma unroll
    for (int j = 0; j < 4; ++j) { ra[j] = *reinterpret_cast<const f32x4*>(pa + j * 4);
                                  rb[j] = *reinterpret_cast<const f32x4*>(pw + j * 4); }

    f32x4 acc[2][2] = {};

    for (int k = 0; k < kit; ++k) {
        __syncthreads();   // prior iter's frag reads done -> LDS reusable
        #pragma unroll
        for (int u = 0; u < 2; ++u) {
            f32x4 a0 = ra[2*u], a1 = ra[2*u+1], b0 = rb[2*u], b1 = rb[2*u+1];
            bf16x8 ha = { (bf16_t)a0.x,(bf16_t)a0.y,(bf16_t)a0.z,(bf16_t)a0.w,
                          (bf16_t)a1.x,(bf16_t)a1.y,(bf16_t)a1.z,(bf16_t)a1.w };
            bf16x8 hb = { (bf16_t)b0.x,(bf16_t)b0.y,(bf16_t)b0.z,(bf16_t)b0.w,
                          (bf16_t)b1.x,(bf16_t)b1.y,(bf16_t)b1.z,(bf16_t)b1.w };
            *reinterpret_cast<bf16x8*>(&As[lr][lc * 16 + u * 8]) = ha;
            *reinterpret_cast<bf16x8*>(&Bs[lr][lc * 16 + u * 8]) = hb;
        }
        if (k + 1 < kit) {   // prefetch next k-slab into regs (latency hidden)
            const float* qa = pa + (k + 1) * 64;
            const float* qw = pw + (k + 1) * 64;
            #pragma unroll
            for (int j = 0; j < 4; ++j) { ra[j] = *reinterpret_cast<const f32x4*>(qa + j * 4);
                                          rb[j] = *reinterpret_cast<const f32x4*>(qw + j * 4); }
        }
        __syncthreads();     // staged tile visible

        #pragma unroll
        for (int s = 0; s < 2; ++s) {
            bf16x8 aF[2], bF[2];
            #pragma unroll
            for (int mf = 0; mf < 2; ++mf)
                aF[mf] = *reinterpret_cast<const bf16x8*>(&As[wy*32 + mf*16 + c16][s*32 + quad*8]);
            #pragma unroll
            for (int nf = 0; nf < 2; ++nf)
                bF[nf] = *reinterpret_cast<const bf16x8*>(&Bs[wx*32 + nf*16 + c16][s*32 + quad*8]);
            #pragma unroll
            for (int mf = 0; mf < 2; ++mf)
                #pragma unroll
                for (int nf = 0; nf < 2; ++nf)
                    acc[mf][nf] = __builtin_amdgcn_mfma_f32_16x16x32_bf16(
                        aF[mf], bF[nf], acc[mf][nf], 0, 0, 0);
        }
    }

    #pragma unroll
    for (int nf = 0; nf < 2; ++nf) {
        int gcol = colBase + wx * 32 + nf * 16 + c16;
        float b = bias[gcol];
        #pragma unroll
        for (int mf = 0; mf < 2; ++mf)
            #pragma unroll
            for (int r = 0; r < 4; ++r) {
                int grow = rowBase + wy * 32 + mf * 16 + quad * 4 + r;
                P[(size_t)grow * 256 + gcol] = acc[mf][nf][r] + b;
            }
    }
}

// ---------------------------------------------------------------------------
// rownorm: L2-normalize rows of Xp/Yp -> bf16. Also zero rowsum/colsum
// (16384 floats, contiguous) so no separate memset dispatch is needed.
// ---------------------------------------------------------------------------
__global__ __launch_bounds__(256) void rownorm(
    const float* __restrict__ Xp, const float* __restrict__ Yp,
    bf16_t* __restrict__ Xn, bf16_t* __restrict__ Yn,
    float* __restrict__ sums)
{
    if (blockIdx.x < 64) sums[blockIdx.x * 256 + threadIdx.x] = 0.0f;

    const int wave = threadIdx.x >> 6;
    const int lane = threadIdx.x & 63;
    const int r = blockIdx.x * 4 + wave;

    const float* src;
    bf16_t* dst;
    int row;
    if (r < 8192) { src = Xp; dst = Xn; row = r; }
    else          { src = Yp; dst = Yn; row = r - 8192; }

    f32x4 v = *reinterpret_cast<const f32x4*>(&src[(size_t)row * 256 + lane * 4]);
    float s = v.x * v.x + v.y * v.y + v.z * v.z + v.w * v.w;
    #pragma unroll
    for (int o = 32; o >= 1; o >>= 1) s += __shfl_xor(s, o, 64);
    float inv = 1.0f / fmaxf(sqrtf(s), 1e-8f);

    bf16x4 h = { (bf16_t)(v.x * inv), (bf16_t)(v.y * inv),
                 (bf16_t)(v.z * inv), (bf16_t)(v.w * inv) };
    *reinterpret_cast<bf16x4*>(&dst[(size_t)row * 256 + lane * 4]) = h;
}

// ---------------------------------------------------------------------------
// sim_gemm: e = exp(Xn @ Yn^T); rowsum/colsum/diag. BM=BN=128, BK=32, 8 iters.
// Double-buffered LDS filled via global_load_lds (16B DMA). XOR chunk swizzle
// (chunk ^ (row>>1)&3) keeps DMA contiguous while making frag reads 2-way.
// One __syncthreads per iter: its vmcnt(0) waits only the prefetch issued a
// full compute phase earlier.
// ---------------------------------------------------------------------------
__global__ __launch_bounds__(256) void sim_gemm(
    const bf16_t* __restrict__ Xn, const bf16_t* __restrict__ Yn,
    float* __restrict__ rowsum, float* __restrict__ colsum,
    float* __restrict__ pos)
{
    __shared__ bf16_t As[2][128][32];
    __shared__ bf16_t Bs[2][128][32];
    __shared__ float  red[256];

    const int tid  = threadIdx.x;
    const int lane = tid & 63;
    const int wave = tid >> 6;
    const int quad = lane >> 4;
    const int c16  = lane & 15;
    const int wy   = wave >> 1;
    const int wx   = wave & 1;
    const int rowBase = blockIdx.x * 128;
    const int colBase = blockIdx.y * 128;

    const int srow = lane >> 2;    // 0..15 row-in-pass
    const int pch  = lane & 3;     // physical 16B chunk

    f32x4 acc[4][4] = {};

    // stage k-slab k0 into buffer b (4 DMA insts/thread)
    auto stage = [&](int k0, int b) {
        #pragma unroll
        for (int t = 0; t < 2; ++t) {
            int r0  = t * 64 + wave * 16;          // wave-uniform
            int row = r0 + srow;
            int sw  = (row >> 1) & 3;
            int col = k0 + ((pch ^ sw) << 3);
            gl_lds16(&Xn[(size_t)(rowBase + row) * 256 + col], &As[b][r0][0]);
            gl_lds16(&Yn[(size_t)(colBase + row) * 256 + col], &Bs[b][r0][0]);
        }
    };

    stage(0, 0);

    for (int k = 0; k < 8; ++k) {
        const int cur = k & 1;
        __syncthreads();                       // drains cur's DMA; orders prev reads
        if (k < 7) stage((k + 1) * 32, cur ^ 1);

        bf16x8 aF[4], bF[4];
        #pragma unroll
        for (int mf = 0; mf < 4; ++mf) {
            int row = wy * 64 + mf * 16 + c16;
            int sw  = (row >> 1) & 3;
            aF[mf] = *reinterpret_cast<const bf16x8*>(&As[cur][row][(quad ^ sw) * 8]);
        }
        #pragma unroll
        for (int nf = 0; nf < 4; ++nf) {
            int row = wx * 64 + nf * 16 + c16;
            int sw  = (row >> 1) & 3;
            bF[nf] = *reinterpret_cast<const bf16x8*>(&Bs[cur][row][(quad ^ sw) * 8]);
        }
        #pragma unroll
        for (int mf = 0; mf < 4; ++mf)
            #pragma unroll
            for (int nf = 0; nf < 4; ++nf)
                acc[mf][nf] = __builtin_amdgcn_mfma_f32_16x16x32_bf16(
                    aF[mf], bF[nf], acc[mf][nf], 0, 0, 0);
    }

    // ---- epilogue ----
    #pragma unroll
    for (int mf = 0; mf < 4; ++mf)
        #pragma unroll
        for (int nf = 0; nf < 4; ++nf)
            #pragma unroll
            for (int r = 0; r < 4; ++r)
                acc[mf][nf][r] = __expf(acc[mf][nf][r]);

    if (rowBase == colBase) {
        #pragma unroll
        for (int mf = 0; mf < 4; ++mf)
            #pragma unroll
            for (int nf = 0; nf < 4; ++nf)
                #pragma unroll
                for (int r = 0; r < 4; ++r) {
                    int lrow = wy * 64 + mf * 16 + quad * 4 + r;
                    int lcol = wx * 64 + nf * 16 + c16;
                    if (lrow == lcol) pos[rowBase + lrow] = acc[mf][nf][r];
                }
    }

    float rs[4][4];
    #pragma unroll
    for (int mf = 0; mf < 4; ++mf)
        #pragma unroll
        for (int r = 0; r < 4; ++r) {
            float v = acc[mf][0][r] + acc[mf][1][r] + acc[mf][2][r] + acc[mf][3][r];
            v += __shfl_xor(v, 1, 64);
            v += __shfl_xor(v, 2, 64);
            v += __shfl_xor(v, 4, 64);
            v += __shfl_xor(v, 8, 64);
            rs[mf][r] = v;
        }

    float cs[4];
    #pragma unroll
    for (int nf = 0; nf < 4; ++nf) {
        float v = 0.f;
        #pragma unroll
        for (int mf = 0; mf < 4; ++mf)
            #pragma unroll
            for (int r = 0; r < 4; ++r)
                v += acc[mf][nf][r];
        v += __shfl_xor(v, 16, 64);
        v += __shfl_xor(v, 32, 64);
        cs[nf] = v;
    }

    red[tid] = 0.f;
    __syncthreads();

    if (c16 == 0) {
        #pragma unroll
        for (int mf = 0; mf < 4; ++mf)
            #pragma unroll
            for (int r = 0; r < 4; ++r)
                atomicAdd(&red[wy * 64 + mf * 16 + quad * 4 + r], rs[mf][r]);
    }
    if (quad == 0) {
        #pragma unroll
        for (int nf = 0; nf < 4; ++nf)
            atomicAdd(&red[128 + wx * 64 + nf * 16 + c16], cs[nf]);
    }
    __syncthreads();

    if (tid < 128) atomicAdd(&rowsum[rowBase + tid], red[tid]);
    else           atomicAdd(&colsum[colBase + tid - 128], red[tid]);
}

// ---------------------------------------------------------------------------
__global__ __launch_bounds__(256) void finalize(
    const float* __restrict__ rowsum, const float* __restrict__ colsum,
    const float* __restrict__ pos, float* __restrict__ out)
{
    int i = blockIdx.x * 256 + threadIdx.x;
    float p = pos[i];
    out[i] = logf(colsum[i] - p) + logf(rowsum[i] - p) - 2.0f * logf(p);
}

// ---------------------------------------------------------------------------
extern "C" void kernel_launch(void* const* d_in, const int* in_sizes, int n_in,
                              void* d_out, int out_size, void* d_ws, size_t ws_size,
                              hipStream_t stream) {
    const float* X  = (const float*)d_in[0];
    const float* Y  = (const float*)d_in[1];
    const float* Wx = (const float*)d_in[2];
    const float* bx = (const float*)d_in[3];
    const float* Wy = (const float*)d_in[4];
    const float* by = (const float*)d_in[5];
    float* out = (float*)d_out;

    char* ws = (char*)d_ws;
    float*  Xp = (float*)(ws);                     // 8 MB
    float*  Yp = (float*)(ws + (8u  << 20));       // 8 MB
    bf16_t* Xn = (bf16_t*)(ws + (16u << 20));      // 4 MB
    bf16_t* Yn = (bf16_t*)(ws + (20u << 20));      // 4 MB
    float*  rowsum = (float*)(ws + (24u << 20));
    float*  colsum = rowsum + 8192;
    float*  pos    = colsum + 8192;

    proj_gemm<<<dim3(256, 4), 256, 0, stream>>>(X, Y, Wx, bx, Wy, by, Xp, Yp);
    rownorm<<<4096, 256, 0, stream>>>(Xp, Yp, Xn, Yn, rowsum);
    sim_gemm<<<dim3(64, 64), 256, 0, stream>>>(Xn, Yn, rowsum, colsum, pos);
    finalize<<<32, 256, 0, stream>>>(rowsum, colsum, pos, out);
}